// Round 12
// baseline (170.150 us; speedup 1.0000x reference)
//
#include <hip/hip_runtime.h>
#include <stdint.h>

typedef unsigned short u16;
typedef unsigned int u32;
typedef __attribute__((ext_vector_type(8))) short short8;
typedef __attribute__((ext_vector_type(4))) float f32x4;
typedef __attribute__((ext_vector_type(8))) unsigned short u16x8;
typedef __attribute__((ext_vector_type(4))) float float4_t;

__device__ __forceinline__ float b2f(u16 u) { return __uint_as_float(((u32)u) << 16); }
__device__ __forceinline__ u16 f2b(float f) {
  u32 u = __float_as_uint(f);
  u += 0x7fffu + ((u >> 16) & 1u);
  return (u16)(u >> 16);
}

typedef const __attribute__((address_space(1))) void* gas_t;
typedef __attribute__((address_space(3))) void* las_t;
__device__ __forceinline__ void gl_lds16(const void* g, void* l) {
  __builtin_amdgcn_global_load_lds((gas_t)(uintptr_t)g, (las_t)(u32)(uintptr_t)l, 16, 0, 0);
}
__device__ __forceinline__ void barrier_pin() {
  __builtin_amdgcn_sched_barrier(0);
  __builtin_amdgcn_s_barrier();
  __builtin_amdgcn_sched_barrier(0);
}
__device__ __forceinline__ void lgkm0_pin() {
  asm volatile("s_waitcnt lgkmcnt(0)" ::: "memory");
  __builtin_amdgcn_sched_barrier(0);  // rule #18
}

// ---------------- fp32 -> bf16 convert (vectorized) ----------------
__global__ __launch_bounds__(256) void cvt_f2b_kernel(const float* __restrict__ src,
                                                      u16* __restrict__ dst, long n) {
  long i = ((long)blockIdx.x * 256 + threadIdx.x) * 8;
  if (i >= n) return;
  float4_t v0 = *(const float4_t*)(src + i);
  float4_t v1 = *(const float4_t*)(src + i + 4);
  u16x8 o;
#pragma unroll
  for (int j = 0; j < 4; ++j) { o[j] = f2b(v0[j]); o[4 + j] = f2b(v1[j]); }
  *(u16x8*)(dst + i) = o;
}

// ------------- fp32 [R][C] -> bf16 [C][R] transpose+convert -------------
__global__ __launch_bounds__(256) void tr_cvt(const float* __restrict__ src,
                                              u16* __restrict__ dst, int R, int C) {
  __shared__ float t[32][33];
  const int bx = blockIdx.x * 32;
  const int by = blockIdx.y * 32;
  const int tx = threadIdx.x & 31, ty = threadIdx.x >> 5;
#pragma unroll
  for (int i = 0; i < 32; i += 8)
    t[ty + i][tx] = src[(long)(by + ty + i) * C + bx + tx];
  __syncthreads();
#pragma unroll
  for (int i = 0; i < 32; i += 8)
    dst[(long)(bx + ty + i) * R + by + tx] = f2b(t[tx][ty + i]);
}

// ------------- V slice of qkv [B][N][1536] -> vt [B][512][2048] (bf16) -------------
__global__ __launch_bounds__(256) void tr_v(const u16* __restrict__ qkv, u16* __restrict__ vt) {
  __shared__ u16 t[32][33];
  const int b = blockIdx.z;
  const int r0 = blockIdx.x * 32;
  const int d0 = blockIdx.y * 32;
  const int tx = threadIdx.x & 31, ty = threadIdx.x >> 5;
#pragma unroll
  for (int i = 0; i < 32; i += 8)
    t[ty + i][tx] = qkv[((long)b * 2048 + r0 + ty + i) * 1536 + 1024 + d0 + tx];
  __syncthreads();
#pragma unroll
  for (int i = 0; i < 32; i += 8)
    vt[((long)b * 512 + d0 + ty + i) * 2048 + r0 + tx] = t[tx][ty + i];
}

// ============ 256x128 BK=32 2-phase BT-GEMM (square 64x64 waves) ============
// C[M][N] = A[M][K] @ Bt[N][K]^T.  BM=256, BN=128, BK=32. 512 thr = 8 waves as
// 4x2 (wr=wid>>1: 64-row band; wc=wid&1: 64-col half). Per-wave C = 64x64 ->
// LDS reads 8 b128/wave/K-tile for 4096 outputs (33% less port traffic per
// output than the 64x32 wave of gemm128 — the measured ~30% plateau's limiter).
// LDS 2buf x (A 16KB + B 8KB) = 48 KB -> 2 blocks/CU. acc 64 VGPR; cap (512,4).
// Phase schedule = verified r9 T3 minimum-2-phase (geometry rescaled only):
//   stage(T+1)->buf^1 (3 gl_lds/thread) ; 8 ds_read tile T ; lgkm0 ;
//   16 MFMA ; vmcnt(0) ; BAR
// k-slot swizzle (both-sides): LDS row r, 8-elem slot s holds global slot
// s^(r&3) (staging thread t: row=t>>2, dest slot t&3, source slot
// (t&3)^((t>>2)&3); dest byte = t*16 -> linear per-wave ✓). Reads use slot
// lg^(lr&3) (row&3 == lr&3 for all frag rows). 8-lane groups: 2-way bank
// aliasing only (free, m136). XCD bijective remap (all grids %8==0).
template <bool OUT_F32, bool BIAS, bool RES, bool EXP_EPI>
__global__ __launch_bounds__(512, 4)
void gemm256n(const u16* __restrict__ A, const u16* __restrict__ Bt, void* __restrict__ Cv,
              const float* __restrict__ bias, const float* __restrict__ res,
              int K, int lda, int ldb, int ldc,
              long aStride, long bStride, long cStride, float alpha) {
  __shared__ u16 As[2][256 * 32];
  __shared__ u16 Bs[2][128 * 32];
  const int tid = threadIdx.x;
  const int wid = tid >> 6, lane = tid & 63;
  const int wr = wid >> 1, wc = wid & 1;
  const int lr = lane & 15, lg = lane >> 4;

  const int gx = gridDim.x, gy = gridDim.y;
  int id = (blockIdx.z * gy + blockIdx.y) * gx + blockIdx.x;
  const int nwg = gx * gy * gridDim.z;
  id = (id & 7) * (nwg >> 3) + (id >> 3);
  const int bxi = id % gx;
  const int t2 = id / gx;
  const int byi = t2 % gy;
  const long z = t2 / gy;

  A += z * aStride;
  Bt += z * bStride;
  const int by = byi * 256;
  const int bx = bxi * 128;

  f32x4 acc[4][4] = {};
  short8 ah[4], bh[4];

  const int th_row = tid >> 2;                         // 0..127
  const int slot_lin = (tid & 3) * 8;                  // dest slot (elems)
  const int slot_src = (((tid & 3) ^ ((tid >> 2) & 3)) * 8);  // pre-swizzled src
  const int nT = K >> 5;
  const int sx = lr & 3;

  const u16* Ag0 = A + (long)(by + th_row) * lda + slot_src;
  const u16* Ag1 = Ag0 + (long)128 * lda;  // rows +128: (row&3) unchanged
  const u16* Bg  = Bt + (long)(bx + th_row) * ldb + slot_src;
  const int dA = th_row * 32 + slot_lin;
  const int dB = dA;

  auto stage = [&](int kt) {
    const int bb = kt & 1;
    const long ko = (long)kt * 32;
    gl_lds16(Ag0 + ko, &As[bb][dA]);
    gl_lds16(Ag1 + ko, &As[bb][dA + 128 * 32]);
    gl_lds16(Bg + ko, &Bs[bb][dB]);
  };

  // -------- prologue --------
  stage(0);
  asm volatile("s_waitcnt vmcnt(0)" ::: "memory");
  barrier_pin();

  // -------- main loop: one phase per K-tile --------
  for (int T = 0; T < nT; ++T) {
    const int bb = T & 1;
    const bool more = (T + 1) < nT;
    if (more) stage(T + 1);
#pragma unroll
    for (int mi = 0; mi < 4; ++mi)
      ah[mi] = *(const short8*)&As[bb][(wr * 64 + mi * 16 + lr) * 32 + ((lg ^ sx) * 8)];
#pragma unroll
    for (int ni = 0; ni < 4; ++ni)
      bh[ni] = *(const short8*)&Bs[bb][(wc * 64 + ni * 16 + lr) * 32 + ((lg ^ sx) * 8)];
    lgkm0_pin();
    __builtin_amdgcn_s_setprio(1);
#pragma unroll
    for (int mi = 0; mi < 4; ++mi)
#pragma unroll
      for (int ni = 0; ni < 4; ++ni)
        acc[mi][ni] = __builtin_amdgcn_mfma_f32_16x16x32_bf16(
            ah[mi], bh[ni], acc[mi][ni], 0, 0, 0);
    __builtin_amdgcn_s_setprio(0);
    if (more) asm volatile("s_waitcnt vmcnt(0)" ::: "memory");
    barrier_pin();
  }

  // -------- epilogue: row = by+wr*64+mi*16+lg*4+j ; col = bx+wc*64+ni*16+lr --------
  if constexpr (EXP_EPI) {
    u16* C = (u16*)Cv + z * cStride;
#pragma unroll
    for (int mi = 0; mi < 4; ++mi)
#pragma unroll
      for (int ni = 0; ni < 4; ++ni)
#pragma unroll
        for (int j = 0; j < 4; ++j) {
          const long row = by + wr * 64 + mi * 16 + lg * 4 + j;
          const int col = bx + wc * 64 + ni * 16 + lr;
          C[row * (long)ldc + col] = f2b(__expf(acc[mi][ni][j] * alpha));
        }
  } else if constexpr (OUT_F32) {
    float* C = (float*)Cv + z * cStride;
#pragma unroll
    for (int mi = 0; mi < 4; ++mi)
#pragma unroll
      for (int ni = 0; ni < 4; ++ni)
#pragma unroll
        for (int j = 0; j < 4; ++j) {
          const long row = by + wr * 64 + mi * 16 + lg * 4 + j;
          const int col = bx + wc * 64 + ni * 16 + lr;
          float v = acc[mi][ni][j] * alpha;
          if (BIAS) v += bias[col];
          if (RES) v += res[row * (long)ldc + col];
          C[row * (long)ldc + col] = v;
        }
  } else {
    u16* C = (u16*)Cv + z * cStride;
#pragma unroll
    for (int mi = 0; mi < 4; ++mi)
#pragma unroll
      for (int ni = 0; ni < 4; ++ni)
#pragma unroll
        for (int j = 0; j < 4; ++j) {
          const long row = by + wr * 64 + mi * 16 + lg * 4 + j;
          const int col = bx + wc * 64 + ni * 16 + lr;
          float v = acc[mi][ni][j] * alpha;
          if (BIAS) v += bias[col];
          C[row * (long)ldc + col] = f2b(v);
        }
  }
}

// ======================= 128x128 2-phase BT-GEMM (PV: rowsum/div) =======================
// Verified rounds 9-11. Used ONLY for PV: O = (Pu@V)/l, l via gated ones-MFMA.
__global__ __launch_bounds__(512, 4)
void gemm128_pv(const u16* __restrict__ A, const u16* __restrict__ Bt, u16* __restrict__ Cv,
                int K, int lda, int ldb, int ldc,
                long aStride, long bStride, long cStride) {
  __shared__ u16 As[2][128 * 64];
  __shared__ u16 Bs[2][128 * 64];
  __shared__ float lsum[128];
  const int tid = threadIdx.x;
  const int wid = tid >> 6, lane = tid & 63;
  const int wr = wid >> 2, wc = wid & 3;
  const int lr = lane & 15, lg = lane >> 4;

  const int gx = gridDim.x, gy = gridDim.y;
  int id = (blockIdx.z * gy + blockIdx.y) * gx + blockIdx.x;
  const int nwg = gx * gy * gridDim.z;
  id = (id & 7) * (nwg >> 3) + (id >> 3);
  const int bxi = id % gx;
  const int t2 = id / gx;
  const int byi = t2 % gy;
  const long z = t2 / gy;

  A += z * aStride;
  Bt += z * bStride;
  const int by = byi * 128;
  const int bx = bxi * 128;

  f32x4 acc[4][2] = {};
  f32x4 acc_l[4] = {};
  short8 ah[4][2], bh[2][2];
  short8 ones;
#pragma unroll
  for (int j = 0; j < 8; ++j) ones[j] = (short)0x3F80;  // bf16 1.0

  const int w8l = wid * 8 + (lane >> 3);
  const int scol_src = ((lane & 7) ^ (lane >> 3)) * 8;
  const int scol_lin = (lane & 7) * 8;
  const int nT = K >> 6;
  const int sx = lane & 7;

  auto stage = [&](int kt) {
    const int bb = kt & 1;
    const long kc = (long)kt * 64 + scol_src;
#pragma unroll
    for (int r = 0; r < 2; ++r) {
      const int row = r * 64 + w8l;
      gl_lds16(A + (long)(by + row) * lda + kc, &As[bb][row * 64 + scol_lin]);
    }
#pragma unroll
    for (int r = 0; r < 2; ++r) {
      const int row = r * 64 + w8l;
      gl_lds16(Bt + (long)(bx + row) * ldb + kc, &Bs[bb][row * 64 + scol_lin]);
    }
  };

  stage(0);
  asm volatile("s_waitcnt vmcnt(0)" ::: "memory");
  barrier_pin();

  for (int T = 0; T < nT; ++T) {
    const int bb = T & 1;
    const bool more = (T + 1) < nT;
    if (more) stage(T + 1);
#pragma unroll
    for (int mi = 0; mi < 4; ++mi)
#pragma unroll
      for (int ks = 0; ks < 2; ++ks)
        ah[mi][ks] = *(const short8*)&As[bb][(wr * 64 + mi * 16 + lr) * 64 +
                                             (((ks * 4 + lg) ^ sx) * 8)];
#pragma unroll
    for (int n = 0; n < 2; ++n)
#pragma unroll
      for (int ks = 0; ks < 2; ++ks)
        bh[n][ks] = *(const short8*)&Bs[bb][(wc * 32 + n * 16 + lr) * 64 +
                                            (((ks * 4 + lg) ^ sx) * 8)];
    lgkm0_pin();
    __builtin_amdgcn_s_setprio(1);
#pragma unroll
    for (int mi = 0; mi < 4; ++mi)
#pragma unroll
      for (int n = 0; n < 2; ++n)
#pragma unroll
        for (int ks = 0; ks < 2; ++ks)
          acc[mi][n] = __builtin_amdgcn_mfma_f32_16x16x32_bf16(
              ah[mi][ks], bh[n][ks], acc[mi][n], 0, 0, 0);
    if (wc == 0) {
#pragma unroll
      for (int mi = 0; mi < 4; ++mi)
#pragma unroll
        for (int ks = 0; ks < 2; ++ks)
          acc_l[mi] = __builtin_amdgcn_mfma_f32_16x16x32_bf16(
              ah[mi][ks], ones, acc_l[mi], 0, 0, 0);
    }
    __builtin_amdgcn_s_setprio(0);
    if (more) asm volatile("s_waitcnt vmcnt(0)" ::: "memory");
    barrier_pin();
  }

  if (wc == 0 && lr == 0) {
#pragma unroll
    for (int mi = 0; mi < 4; ++mi)
#pragma unroll
      for (int j = 0; j < 4; ++j)
        lsum[wr * 64 + mi * 16 + lg * 4 + j] = acc_l[mi][j];
  }
  __syncthreads();

  u16* C = Cv + z * cStride;
#pragma unroll
  for (int mi = 0; mi < 4; ++mi)
#pragma unroll
    for (int j = 0; j < 4; ++j) {
      const float invl = 1.0f / lsum[wr * 64 + mi * 16 + lg * 4 + j];
#pragma unroll
      for (int ni = 0; ni < 2; ++ni) {
        const long row = by + wr * 64 + mi * 16 + lg * 4 + j;
        const int col = bx + wc * 32 + ni * 16 + lr;
        C[row * (long)ldc + col] = f2b(acc[mi][ni][j] * invl);
      }
    }
}

extern "C" void kernel_launch(void* const* d_in, const int* in_sizes, int n_in,
                              void* d_out, int out_size, void* d_ws, size_t ws_size,
                              hipStream_t stream) {
  const float* x = (const float*)d_in[0];      // [8,2048,512]
  const float* w_qkv = (const float*)d_in[1];  // [512,1536]
  const float* b_qkv = (const float*)d_in[2];  // [1536]
  const float* w_fc = (const float*)d_in[3];   // [512,512]
  const float* b_fc = (const float*)d_in[4];   // [512]
  float* out = (float*)d_out;                  // [8,2048,512] f32

  char* ws = (char*)d_ws;
  const long MT = 16384;
  u16* xb = (u16*)(ws);                    // 16 MB  [16384][512]   (reused as attn_out)
  u16* wqkvT = (u16*)(ws + 16777216);      // 1.5 MB [1536][512]
  u16* wfcT = (u16*)(ws + 18350080);       // 0.5 MB [512][512]
  u16* qkv = (u16*)(ws + 18874368);        // 48 MB  [16384][1536]
  u16* vt = (u16*)(ws + 69206016);         // 16 MB  [8][512][2048]
  u16* S = (u16*)(ws + 85983232);          // 64 MB  [8][2048][2048]  (Pu)
  u16* attn = xb;

  cvt_f2b_kernel<<<4096, 256, 0, stream>>>(x, xb, MT * 512);
  tr_cvt<<<dim3(48, 16), 256, 0, stream>>>(w_qkv, wqkvT, 512, 1536);
  tr_cvt<<<dim3(16, 16), 256, 0, stream>>>(w_fc, wfcT, 512, 512);

  // qkv = x @ w_qkv + b_qkv   [16384 x 1536], K=512  (64x12 -> 768 blocks)
  gemm256n<false, true, false, false><<<dim3(12, 64, 1), 512, 0, stream>>>(
      xb, wqkvT, qkv, b_qkv, nullptr,
      512, 512, 512, 1536, 0, 0, 0, 1.0f);

  tr_v<<<dim3(64, 16, 8), 256, 0, stream>>>(qkv, vt);

  // Pu = exp(scale * Q @ K^T) per batch [2048 x 2048], K=512  (16x8x8 -> 1024)
  gemm256n<false, false, false, true><<<dim3(16, 8, 8), 512, 0, stream>>>(
      qkv, qkv + 512, S, nullptr, nullptr,
      512, 1536, 1536, 2048,
      (long)2048 * 1536, (long)2048 * 1536, (long)2048 * 2048, 0.04419417382415922f);

  // attn = (Pu @ V) / l  per batch [2048 x 512], K=2048 (proven gemm128 path)
  gemm128_pv<<<dim3(4, 16, 8), 512, 0, stream>>>(
      S, vt, attn,
      2048, 2048, 2048, 512,
      (long)2048 * 2048, (long)512 * 2048, (long)2048 * 512);

  // out = attn @ w_fc + b_fc + x  [16384 x 512], K=512  (4x64 -> 256 blocks)
  gemm256n<true, true, true, false><<<dim3(4, 64, 1), 512, 0, stream>>>(
      attn, wfcT, out, b_fc, x,
      512, 512, 512, 512, 0, 0, 0, 1.0f);
}

// Round 13
// 168.224 us; speedup vs baseline: 1.0115x; 1.0115x over previous
//
#include <hip/hip_runtime.h>
#include <stdint.h>

typedef unsigned short u16;
typedef unsigned int u32;
typedef __attribute__((ext_vector_type(8))) short short8;
typedef __attribute__((ext_vector_type(4))) float f32x4;
typedef __attribute__((ext_vector_type(8))) unsigned short u16x8;
typedef __attribute__((ext_vector_type(4))) float float4_t;

__device__ __forceinline__ float b2f(u16 u) { return __uint_as_float(((u32)u) << 16); }
__device__ __forceinline__ u16 f2b(float f) {
  u32 u = __float_as_uint(f);
  u += 0x7fffu + ((u >> 16) & 1u);
  return (u16)(u >> 16);
}

typedef const __attribute__((address_space(1))) void* gas_t;
typedef __attribute__((address_space(3))) void* las_t;
__device__ __forceinline__ void gl_lds16(const void* g, void* l) {
  __builtin_amdgcn_global_load_lds((gas_t)(uintptr_t)g, (las_t)(u32)(uintptr_t)l, 16, 0, 0);
}
__device__ __forceinline__ void barrier_pin() {
  __builtin_amdgcn_sched_barrier(0);
  __builtin_amdgcn_s_barrier();
  __builtin_amdgcn_sched_barrier(0);
}
__device__ __forceinline__ void lgkm0_pin() {
  asm volatile("s_waitcnt lgkmcnt(0)" ::: "memory");
  __builtin_amdgcn_sched_barrier(0);  // rule #18
}

// ---------------- fp32 -> bf16 convert (vectorized) ----------------
__global__ __launch_bounds__(256) void cvt_f2b_kernel(const float* __restrict__ src,
                                                      u16* __restrict__ dst, long n) {
  long i = ((long)blockIdx.x * 256 + threadIdx.x) * 8;
  if (i >= n) return;
  float4_t v0 = *(const float4_t*)(src + i);
  float4_t v1 = *(const float4_t*)(src + i + 4);
  u16x8 o;
#pragma unroll
  for (int j = 0; j < 4; ++j) { o[j] = f2b(v0[j]); o[4 + j] = f2b(v1[j]); }
  *(u16x8*)(dst + i) = o;
}

// ------------- fp32 [R][C] -> bf16 [C][R] transpose+convert -------------
__global__ __launch_bounds__(256) void tr_cvt(const float* __restrict__ src,
                                              u16* __restrict__ dst, int R, int C) {
  __shared__ float t[32][33];
  const int bx = blockIdx.x * 32;
  const int by = blockIdx.y * 32;
  const int tx = threadIdx.x & 31, ty = threadIdx.x >> 5;
#pragma unroll
  for (int i = 0; i < 32; i += 8)
    t[ty + i][tx] = src[(long)(by + ty + i) * C + bx + tx];
  __syncthreads();
#pragma unroll
  for (int i = 0; i < 32; i += 8)
    dst[(long)(bx + ty + i) * R + by + tx] = f2b(t[tx][ty + i]);
}

// ------------- V slice of qkv [B][N][1536] -> vt [B][512][2048] (bf16) -------------
__global__ __launch_bounds__(256) void tr_v(const u16* __restrict__ qkv, u16* __restrict__ vt) {
  __shared__ u16 t[32][33];
  const int b = blockIdx.z;
  const int r0 = blockIdx.x * 32;
  const int d0 = blockIdx.y * 32;
  const int tx = threadIdx.x & 31, ty = threadIdx.x >> 5;
#pragma unroll
  for (int i = 0; i < 32; i += 8)
    t[ty + i][tx] = qkv[((long)b * 2048 + r0 + ty + i) * 1536 + 1024 + d0 + tx];
  __syncthreads();
#pragma unroll
  for (int i = 0; i < 32; i += 8)
    vt[((long)b * 512 + d0 + ty + i) * 2048 + r0 + tx] = t[tx][ty + i];
}

// ============ 256x128 BK=32 2-phase BT-GEMM (square 64x64 waves) ============
// Same as round 12 EXCEPT the swizzle key (round-12 bug: SQ_LDS_BANK_CONFLICT
// 4.19M). With 64B rows, a b128's bank-quad = 4*(row&1) + slot, so the XOR key
// must be f(row) = (row>>1)&3 (row bits 1-2), NOT row&3:
//   quad = 4*(row&1) + (lg ^ ((row>>1)&3)) -> permutation of 0..7 over any 8
//   consecutive rows -> conflict-free.
// Staging thread t: dest row t>>2, dest slot t&3 (dest byte = t*16, linear ✓),
// source slot (t&3) ^ f(t>>2) = (t&3) ^ ((t>>3)&3).
// Read rows = base16k + lr -> f(row) = (lr>>1)&3.
template <bool OUT_F32, bool BIAS, bool RES, bool EXP_EPI>
__global__ __launch_bounds__(512, 4)
void gemm256n(const u16* __restrict__ A, const u16* __restrict__ Bt, void* __restrict__ Cv,
              const float* __restrict__ bias, const float* __restrict__ res,
              int K, int lda, int ldb, int ldc,
              long aStride, long bStride, long cStride, float alpha) {
  __shared__ u16 As[2][256 * 32];
  __shared__ u16 Bs[2][128 * 32];
  const int tid = threadIdx.x;
  const int wid = tid >> 6, lane = tid & 63;
  const int wr = wid >> 1, wc = wid & 1;
  const int lr = lane & 15, lg = lane >> 4;

  const int gx = gridDim.x, gy = gridDim.y;
  int id = (blockIdx.z * gy + blockIdx.y) * gx + blockIdx.x;
  const int nwg = gx * gy * gridDim.z;
  id = (id & 7) * (nwg >> 3) + (id >> 3);
  const int bxi = id % gx;
  const int t2 = id / gx;
  const int byi = t2 % gy;
  const long z = t2 / gy;

  A += z * aStride;
  Bt += z * bStride;
  const int by = byi * 256;
  const int bx = bxi * 128;

  f32x4 acc[4][4] = {};
  short8 ah[4], bh[4];

  const int th_row = tid >> 2;                                  // 0..127
  const int slot_lin = (tid & 3) * 8;                           // dest slot (elems)
  const int slot_src = (((tid & 3) ^ ((tid >> 3) & 3)) * 8);    // FIXED: f(row)=(row>>1)&3
  const int nT = K >> 5;
  const int sx = (lr >> 1) & 3;                                 // FIXED read key

  const u16* Ag0 = A + (long)(by + th_row) * lda + slot_src;
  const u16* Ag1 = Ag0 + (long)128 * lda;  // rows +128: bits 1-2 unchanged
  const u16* Bg  = Bt + (long)(bx + th_row) * ldb + slot_src;
  const int dA = th_row * 32 + slot_lin;
  const int dB = dA;

  auto stage = [&](int kt) {
    const int bb = kt & 1;
    const long ko = (long)kt * 32;
    gl_lds16(Ag0 + ko, &As[bb][dA]);
    gl_lds16(Ag1 + ko, &As[bb][dA + 128 * 32]);
    gl_lds16(Bg + ko, &Bs[bb][dB]);
  };

  // -------- prologue --------
  stage(0);
  asm volatile("s_waitcnt vmcnt(0)" ::: "memory");
  barrier_pin();

  // -------- main loop: one phase per K-tile --------
  for (int T = 0; T < nT; ++T) {
    const int bb = T & 1;
    const bool more = (T + 1) < nT;
    if (more) stage(T + 1);
#pragma unroll
    for (int mi = 0; mi < 4; ++mi)
      ah[mi] = *(const short8*)&As[bb][(wr * 64 + mi * 16 + lr) * 32 + ((lg ^ sx) * 8)];
#pragma unroll
    for (int ni = 0; ni < 4; ++ni)
      bh[ni] = *(const short8*)&Bs[bb][(wc * 64 + ni * 16 + lr) * 32 + ((lg ^ sx) * 8)];
    lgkm0_pin();
    __builtin_amdgcn_s_setprio(1);
#pragma unroll
    for (int mi = 0; mi < 4; ++mi)
#pragma unroll
      for (int ni = 0; ni < 4; ++ni)
        acc[mi][ni] = __builtin_amdgcn_mfma_f32_16x16x32_bf16(
            ah[mi], bh[ni], acc[mi][ni], 0, 0, 0);
    __builtin_amdgcn_s_setprio(0);
    if (more) asm volatile("s_waitcnt vmcnt(0)" ::: "memory");
    barrier_pin();
  }

  // -------- epilogue: row = by+wr*64+mi*16+lg*4+j ; col = bx+wc*64+ni*16+lr --------
  if constexpr (EXP_EPI) {
    u16* C = (u16*)Cv + z * cStride;
#pragma unroll
    for (int mi = 0; mi < 4; ++mi)
#pragma unroll
      for (int ni = 0; ni < 4; ++ni)
#pragma unroll
        for (int j = 0; j < 4; ++j) {
          const long row = by + wr * 64 + mi * 16 + lg * 4 + j;
          const int col = bx + wc * 64 + ni * 16 + lr;
          C[row * (long)ldc + col] = f2b(__expf(acc[mi][ni][j] * alpha));
        }
  } else if constexpr (OUT_F32) {
    float* C = (float*)Cv + z * cStride;
#pragma unroll
    for (int mi = 0; mi < 4; ++mi)
#pragma unroll
      for (int ni = 0; ni < 4; ++ni)
#pragma unroll
        for (int j = 0; j < 4; ++j) {
          const long row = by + wr * 64 + mi * 16 + lg * 4 + j;
          const int col = bx + wc * 64 + ni * 16 + lr;
          float v = acc[mi][ni][j] * alpha;
          if (BIAS) v += bias[col];
          if (RES) v += res[row * (long)ldc + col];
          C[row * (long)ldc + col] = v;
        }
  } else {
    u16* C = (u16*)Cv + z * cStride;
#pragma unroll
    for (int mi = 0; mi < 4; ++mi)
#pragma unroll
      for (int ni = 0; ni < 4; ++ni)
#pragma unroll
        for (int j = 0; j < 4; ++j) {
          const long row = by + wr * 64 + mi * 16 + lg * 4 + j;
          const int col = bx + wc * 64 + ni * 16 + lr;
          float v = acc[mi][ni][j] * alpha;
          if (BIAS) v += bias[col];
          C[row * (long)ldc + col] = f2b(v);
        }
  }
}

// ======================= 128x128 2-phase BT-GEMM (PV: rowsum/div) =======================
// Verified rounds 9-11. Used ONLY for PV: O = (Pu@V)/l, l via gated ones-MFMA.
__global__ __launch_bounds__(512, 4)
void gemm128_pv(const u16* __restrict__ A, const u16* __restrict__ Bt, u16* __restrict__ Cv,
                int K, int lda, int ldb, int ldc,
                long aStride, long bStride, long cStride) {
  __shared__ u16 As[2][128 * 64];
  __shared__ u16 Bs[2][128 * 64];
  __shared__ float lsum[128];
  const int tid = threadIdx.x;
  const int wid = tid >> 6, lane = tid & 63;
  const int wr = wid >> 2, wc = wid & 3;
  const int lr = lane & 15, lg = lane >> 4;

  const int gx = gridDim.x, gy = gridDim.y;
  int id = (blockIdx.z * gy + blockIdx.y) * gx + blockIdx.x;
  const int nwg = gx * gy * gridDim.z;
  id = (id & 7) * (nwg >> 3) + (id >> 3);
  const int bxi = id % gx;
  const int t2 = id / gx;
  const int byi = t2 % gy;
  const long z = t2 / gy;

  A += z * aStride;
  Bt += z * bStride;
  const int by = byi * 128;
  const int bx = bxi * 128;

  f32x4 acc[4][2] = {};
  f32x4 acc_l[4] = {};
  short8 ah[4][2], bh[2][2];
  short8 ones;
#pragma unroll
  for (int j = 0; j < 8; ++j) ones[j] = (short)0x3F80;  // bf16 1.0

  const int w8l = wid * 8 + (lane >> 3);
  const int scol_src = ((lane & 7) ^ (lane >> 3)) * 8;
  const int scol_lin = (lane & 7) * 8;
  const int nT = K >> 6;
  const int sx = lane & 7;

  auto stage = [&](int kt) {
    const int bb = kt & 1;
    const long kc = (long)kt * 64 + scol_src;
#pragma unroll
    for (int r = 0; r < 2; ++r) {
      const int row = r * 64 + w8l;
      gl_lds16(A + (long)(by + row) * lda + kc, &As[bb][row * 64 + scol_lin]);
    }
#pragma unroll
    for (int r = 0; r < 2; ++r) {
      const int row = r * 64 + w8l;
      gl_lds16(Bt + (long)(bx + row) * ldb + kc, &Bs[bb][row * 64 + scol_lin]);
    }
  };

  stage(0);
  asm volatile("s_waitcnt vmcnt(0)" ::: "memory");
  barrier_pin();

  for (int T = 0; T < nT; ++T) {
    const int bb = T & 1;
    const bool more = (T + 1) < nT;
    if (more) stage(T + 1);
#pragma unroll
    for (int mi = 0; mi < 4; ++mi)
#pragma unroll
      for (int ks = 0; ks < 2; ++ks)
        ah[mi][ks] = *(const short8*)&As[bb][(wr * 64 + mi * 16 + lr) * 64 +
                                             (((ks * 4 + lg) ^ sx) * 8)];
#pragma unroll
    for (int n = 0; n < 2; ++n)
#pragma unroll
      for (int ks = 0; ks < 2; ++ks)
        bh[n][ks] = *(const short8*)&Bs[bb][(wc * 32 + n * 16 + lr) * 64 +
                                            (((ks * 4 + lg) ^ sx) * 8)];
    lgkm0_pin();
    __builtin_amdgcn_s_setprio(1);
#pragma unroll
    for (int mi = 0; mi < 4; ++mi)
#pragma unroll
      for (int n = 0; n < 2; ++n)
#pragma unroll
        for (int ks = 0; ks < 2; ++ks)
          acc[mi][n] = __builtin_amdgcn_mfma_f32_16x16x32_bf16(
              ah[mi][ks], bh[n][ks], acc[mi][n], 0, 0, 0);
    if (wc == 0) {
#pragma unroll
      for (int mi = 0; mi < 4; ++mi)
#pragma unroll
        for (int ks = 0; ks < 2; ++ks)
          acc_l[mi] = __builtin_amdgcn_mfma_f32_16x16x32_bf16(
              ah[mi][ks], ones, acc_l[mi], 0, 0, 0);
    }
    __builtin_amdgcn_s_setprio(0);
    if (more) asm volatile("s_waitcnt vmcnt(0)" ::: "memory");
    barrier_pin();
  }

  if (wc == 0 && lr == 0) {
#pragma unroll
    for (int mi = 0; mi < 4; ++mi)
#pragma unroll
      for (int j = 0; j < 4; ++j)
        lsum[wr * 64 + mi * 16 + lg * 4 + j] = acc_l[mi][j];
  }
  __syncthreads();

  u16* C = Cv + z * cStride;
#pragma unroll
  for (int mi = 0; mi < 4; ++mi)
#pragma unroll
    for (int j = 0; j < 4; ++j) {
      const float invl = 1.0f / lsum[wr * 64 + mi * 16 + lg * 4 + j];
#pragma unroll
      for (int ni = 0; ni < 2; ++ni) {
        const long row = by + wr * 64 + mi * 16 + lg * 4 + j;
        const int col = bx + wc * 32 + ni * 16 + lr;
        C[row * (long)ldc + col] = f2b(acc[mi][ni][j] * invl);
      }
    }
}

extern "C" void kernel_launch(void* const* d_in, const int* in_sizes, int n_in,
                              void* d_out, int out_size, void* d_ws, size_t ws_size,
                              hipStream_t stream) {
  const float* x = (const float*)d_in[0];      // [8,2048,512]
  const float* w_qkv = (const float*)d_in[1];  // [512,1536]
  const float* b_qkv = (const float*)d_in[2];  // [1536]
  const float* w_fc = (const float*)d_in[3];   // [512,512]
  const float* b_fc = (const float*)d_in[4];   // [512]
  float* out = (float*)d_out;                  // [8,2048,512] f32

  char* ws = (char*)d_ws;
  const long MT = 16384;
  u16* xb = (u16*)(ws);                    // 16 MB  [16384][512]   (reused as attn_out)
  u16* wqkvT = (u16*)(ws + 16777216);      // 1.5 MB [1536][512]
  u16* wfcT = (u16*)(ws + 18350080);       // 0.5 MB [512][512]
  u16* qkv = (u16*)(ws + 18874368);        // 48 MB  [16384][1536]
  u16* vt = (u16*)(ws + 69206016);         // 16 MB  [8][512][2048]
  u16* S = (u16*)(ws + 85983232);          // 64 MB  [8][2048][2048]  (Pu)
  u16* attn = xb;

  cvt_f2b_kernel<<<4096, 256, 0, stream>>>(x, xb, MT * 512);
  tr_cvt<<<dim3(48, 16), 256, 0, stream>>>(w_qkv, wqkvT, 512, 1536);
  tr_cvt<<<dim3(16, 16), 256, 0, stream>>>(w_fc, wfcT, 512, 512);

  // qkv = x @ w_qkv + b_qkv   [16384 x 1536], K=512  (64x12 -> 768 blocks)
  gemm256n<false, true, false, false><<<dim3(12, 64, 1), 512, 0, stream>>>(
      xb, wqkvT, qkv, b_qkv, nullptr,
      512, 512, 512, 1536, 0, 0, 0, 1.0f);

  tr_v<<<dim3(64, 16, 8), 256, 0, stream>>>(qkv, vt);

  // Pu = exp(scale * Q @ K^T) per batch [2048 x 2048], K=512  (16x8x8 -> 1024)
  gemm256n<false, false, false, true><<<dim3(16, 8, 8), 512, 0, stream>>>(
      qkv, qkv + 512, S, nullptr, nullptr,
      512, 1536, 1536, 2048,
      (long)2048 * 1536, (long)2048 * 1536, (long)2048 * 2048, 0.04419417382415922f);

  // attn = (Pu @ V) / l  per batch [2048 x 512], K=2048 (proven gemm128 path)
  gemm128_pv<<<dim3(4, 16, 8), 512, 0, stream>>>(
      S, vt, attn,
      2048, 2048, 2048, 512,
      (long)2048 * 2048, (long)512 * 2048, (long)2048 * 512);

  // out = attn @ w_fc + b_fc + x  [16384 x 512], K=512  (4x64 -> 256 blocks)
  gemm256n<true, true, true, false><<<dim3(4, 64, 1), 512, 0, stream>>>(
      attn, wfcT, out, b_fc, x,
      512, 512, 512, 512, 0, 0, 0, 1.0f);
}